// Round 1
// baseline (1865.853 us; speedup 1.0000x reference)
//
#include <hip/hip_runtime.h>
#include <cstdint>

#define NLAYERS 4
#define TILE_E 32
#define TILE_N 8

__device__ __forceinline__ float silu_f(float x){ return x / (1.f + __expf(-x)); }

// ---------------- init: h_s = embed[z], h_v=h_t=0, readout accumulators ----------------
__global__ void k_init(const int* __restrict__ z, const float* __restrict__ embed,
                       float* __restrict__ hs, float* __restrict__ hv, float* __restrict__ ht,
                       unsigned* __restrict__ mkey, float* __restrict__ den, float* __restrict__ cbuf,
                       int N, int G){
  int idx = blockIdx.x*blockDim.x + threadIdx.x;
  if (idx < N*64) hs[idx] = embed[z[idx>>6]*64 + (idx&63)];
  if (idx < N*96) hv[idx] = 0.f;
  if (idx < N*80) ht[idx] = 0.f;
  if (idx < G) { mkey[idx] = 0u; den[idx] = 0.f; }
  if (idx < G*64) cbuf[idx] = 0.f;
}

// ---------------- per-edge static features: rb (10) and Y (9) ----------------
__global__ void k_efeat(const float* __restrict__ pos, const int* __restrict__ src,
                        const int* __restrict__ dst,
                        float* __restrict__ rbbuf, float* __restrict__ ybuf, int E){
  int e = blockIdx.x*blockDim.x + threadIdx.x;
  if (e >= E) return;
  int s = src[e], d = dst[e];
  float vx = pos[d*3+0]-pos[s*3+0];
  float vy = pos[d*3+1]-pos[s*3+1];
  float vz = pos[d*3+2]-pos[s*3+2];
  float elen = sqrtf(vx*vx+vy*vy+vz*vz);
  float inv = 1.f/(elen+1e-9f);
  float x = vx*inv, y = vy*inv, zc = vz*inv;
  const float s3 = 1.7320508075688772f, s5 = 2.2360679774997896f, s15 = 3.872983346207417f;
  ybuf[e*9+0] = 1.f;
  ybuf[e*9+1] = s3*x;  ybuf[e*9+2] = s3*y;  ybuf[e*9+3] = s3*zc;
  ybuf[e*9+4] = s15*x*y; ybuf[e*9+5] = s15*y*zc;
  ybuf[e*9+6] = 0.5f*s5*(3.f*zc*zc-1.f);
  ybuf[e*9+7] = s15*x*zc; ybuf[e*9+8] = 0.5f*s15*(x*x-y*y);
  const float sigma = 5.0f/9.0f;
  #pragma unroll
  for (int k=0;k<10;k++){
    float c = (5.0f/9.0f)*(float)k;
    float t = (elen - c)/sigma;
    rbbuf[e*10+k] = __expf(-0.5f*t*t);
  }
}

// ---------------- edge kernel: radial MLP -> wgt -> messages -> atomic scatter ----------------
__global__ __launch_bounds__(320) void k_edge(
    const float* __restrict__ hs, const float* __restrict__ hv, const float* __restrict__ ht,
    const int* __restrict__ srcArr, const int* __restrict__ dstArr,
    const float* __restrict__ rbbuf, const float* __restrict__ ybuf,
    const float* __restrict__ rW1, const float* __restrict__ rb1, const float* __restrict__ rW2,
    float* __restrict__ a0, float* __restrict__ a1, float* __restrict__ a2,
    int E, int l)
{
  __shared__ float hid[TILE_E][32];
  __shared__ float swgt[320];
  __shared__ float sS[64];
  __shared__ float sV[96];
  __shared__ float sT[80];
  __shared__ float sY[9];
  int t = threadIdx.x;
  int e0 = blockIdx.x*TILE_E;

  // phase A: hidden = silu(rb@rW1 + rb1) for TILE_E edges
  for (int idx=t; idx<TILE_E*32; idx+=320){
    int el = idx>>5, j = idx&31;
    int e = e0+el;
    if (e < E){
      float acc = rb1[l*32+j];
      const float* rbp = rbbuf + (size_t)e*10;
      const float* w1p = rW1 + (l*10)*32 + j;
      #pragma unroll
      for (int k=0;k<10;k++) acc += rbp[k]*w1p[k*32];
      hid[el][j] = silu_f(acc);
    }
  }
  // phase B: thread t owns rW2 column t (coalesced per j)
  float wcol[32];
  {
    const float* w2p = rW2 + (size_t)(l*32)*320 + t;
    #pragma unroll
    for (int j=0;j<32;j++) wcol[j] = w2p[(size_t)j*320];
  }
  __syncthreads();

  for (int el=0; el<TILE_E; el++){
    int e = e0+el;
    if (e >= E) break;            // uniform across block
    int s_ = srcArr[e];
    // wgt[t] for this edge
    float acc = 0.f;
    #pragma unroll
    for (int j=0;j<32;j++) acc += hid[el][j]*wcol[j];
    swgt[t] = acc;
    // stage source-node rows + Y
    if (t < 64)        sS[t]      = hs[(size_t)s_*64 + t];
    else if (t < 160)  sV[t-64]   = hv[(size_t)s_*96 + (t-64)];
    else if (t < 240)  sT[t-160]  = ht[(size_t)s_*80 + (t-160)];
    else if (t < 249)  sY[t-240]  = ybuf[(size_t)e*9 + (t-240)];
    __syncthreads();
    int d_ = dstArr[e];
    // 896 message components over 320 threads
    for (int idx=t; idx<896; idx+=320){
      float val; float* addr;
      if (idx < 112){
        int c = idx;
        if (c < 64) val = swgt[c]*sS[c];
        else if (c < 96){
          int cc = c-64;
          val = swgt[c]*(sV[cc*3+0]*sY[1] + sV[cc*3+1]*sY[2] + sV[cc*3+2]*sY[3]);
        } else {
          int cc = c-96;
          float a2c = 0.f;
          #pragma unroll
          for (int d2=0; d2<5; d2++) a2c += sT[cc*5+d2]*sY[4+d2];
          val = swgt[c]*a2c;
        }
        addr = &a0[(size_t)d_*112 + c];
      } else if (idx < 496){
        int r = idx-112;
        int c = r/3, dd = r - c*3;
        if (c < 64)      val = swgt[112+c]*sS[c]*sY[1+dd];
        else if (c < 96) val = swgt[176+(c-64)]*sV[(c-64)*3+dd];
        else {
          int cc = c-96;
          int d1 = dd+1; if (d1>=3) d1-=3;
          int d2 = dd+2; if (d2>=3) d2-=3;
          val = swgt[208+cc]*(sV[cc*3+d1]*sY[1+d2] - sV[cc*3+d2]*sY[1+d1]);
        }
        addr = &a1[(size_t)d_*384 + r];
      } else {
        int r = idx-496;
        int c = r/5, dd = r - c*5;
        if (c < 64) val = swgt[240+c]*sS[c]*sY[4+dd];
        else        val = swgt[304+(c-64)]*sT[(c-64)*5+dd];
        addr = &a2[(size_t)d_*400 + r];
      }
      atomicAdd(addr, val);
    }
    __syncthreads();
  }
}

// ---------------- node update: h_s/h_v/h_t <- dense mixes of (a, h) ----------------
__global__ __launch_bounds__(256) void k_node(
    float* __restrict__ hs, float* __restrict__ hv, float* __restrict__ ht,
    const float* __restrict__ a0, const float* __restrict__ a1, const float* __restrict__ a2,
    const float* __restrict__ Ws, const float* __restrict__ Wss,
    const float* __restrict__ Wv, const float* __restrict__ Wvv,
    const float* __restrict__ Wt, const float* __restrict__ Wtt,
    int N, int l)
{
  __shared__ float sA0[TILE_N][112];
  __shared__ float sHs[TILE_N][64];
  __shared__ float sA1[TILE_N][384];
  __shared__ float sHv[TILE_N][96];
  __shared__ float sA2[TILE_N][400];
  __shared__ float sHt[TILE_N][80];
  int t = threadIdx.x;
  int n0 = blockIdx.x*TILE_N;
  int nmax = min(TILE_N, N-n0);

  for (int idx=t; idx<nmax*112; idx+=256){ int n=idx/112, c=idx-n*112; sA0[n][c]=a0[(size_t)(n0+n)*112+c]; }
  for (int idx=t; idx<nmax*64;  idx+=256){ int n=idx>>6,  c=idx&63;    sHs[n][c]=hs[(size_t)(n0+n)*64+c]; }
  for (int idx=t; idx<nmax*384; idx+=256){ int n=idx/384, c=idx-n*384; sA1[n][c]=a1[(size_t)(n0+n)*384+c]; }
  for (int idx=t; idx<nmax*96;  idx+=256){ int n=idx/96,  c=idx-n*96;  sHv[n][c]=hv[(size_t)(n0+n)*96+c]; }
  for (int idx=t; idx<nmax*400; idx+=256){ int n=idx/400, c=idx-n*400; sA2[n][c]=a2[(size_t)(n0+n)*400+c]; }
  for (int idx=t; idx<nmax*80;  idx+=256){ int n=idx/80,  c=idx-n*80;  sHt[n][c]=ht[(size_t)(n0+n)*80+c]; }
  __syncthreads();

  float acc[TILE_N];
  #pragma unroll
  for (int n=0;n<TILE_N;n++) acc[n] = 0.f;

  if (t < 64){
    int f = t;
    for (int c=0;c<112;c++){
      float w = Ws[((size_t)l*112+c)*64+f];
      #pragma unroll
      for (int n=0;n<TILE_N;n++) acc[n] += sA0[n][c]*w;
    }
    for (int c=0;c<64;c++){
      float w = Wss[((size_t)l*64+c)*64+f];
      #pragma unroll
      for (int n=0;n<TILE_N;n++) acc[n] += sHs[n][c]*w;
    }
    for (int n=0;n<nmax;n++) hs[(size_t)(n0+n)*64+f] = silu_f(acc[n]);
  } else if (t < 160){
    int r = t-64, f = r/3, dd = r - f*3;
    for (int c=0;c<128;c++){
      float w = Wv[((size_t)l*128+c)*32+f];
      #pragma unroll
      for (int n=0;n<TILE_N;n++) acc[n] += sA1[n][c*3+dd]*w;
    }
    for (int c=0;c<32;c++){
      float w = Wvv[((size_t)l*32+c)*32+f];
      #pragma unroll
      for (int n=0;n<TILE_N;n++) acc[n] += sHv[n][c*3+dd]*w;
    }
    for (int n=0;n<nmax;n++) hv[(size_t)(n0+n)*96+f*3+dd] = acc[n];
  } else if (t < 240){
    int r = t-160, f = r/5, dd = r - f*5;
    for (int c=0;c<80;c++){
      float w = Wt[((size_t)l*80+c)*16+f];
      #pragma unroll
      for (int n=0;n<TILE_N;n++) acc[n] += sA2[n][c*5+dd]*w;
    }
    for (int c=0;c<16;c++){
      float w = Wtt[((size_t)l*16+c)*16+f];
      #pragma unroll
      for (int n=0;n<TILE_N;n++) acc[n] += sHt[n][c*5+dd]*w;
    }
    for (int n=0;n<nmax;n++) ht[(size_t)(n0+n)*80+f*5+dd] = acc[n];
  }
}

// ---------------- readout ----------------
__global__ __launch_bounds__(64) void k_q(const float* __restrict__ hs, const int* __restrict__ absorber,
                                          const float* __restrict__ Wq, float* __restrict__ qbuf, int G){
  __shared__ float sH[64];
  int g = blockIdx.x, f = threadIdx.x;
  int a = absorber[g];
  sH[f] = hs[(size_t)a*64+f];
  __syncthreads();
  float acc = 0.f;
  for (int c=0;c<64;c++) acc += sH[c]*Wq[c*64+f];
  qbuf[(size_t)g*64+f] = acc;
}

__global__ __launch_bounds__(64) void k_kv(const float* __restrict__ hs,
                                           const float* __restrict__ Wk, const float* __restrict__ Wvp,
                                           float* __restrict__ kbuf, float* __restrict__ vbuf, int N){
  __shared__ float sH[8][64];
  int t = threadIdx.x;
  int n0 = blockIdx.x*8;
  int nmax = min(8, N-n0);
  for (int idx=t; idx<nmax*64; idx+=64){ int n=idx>>6, c=idx&63; sH[n][c]=hs[(size_t)(n0+n)*64+c]; }
  __syncthreads();
  float ka[8], va[8];
  #pragma unroll
  for (int n=0;n<8;n++){ ka[n]=0.f; va[n]=0.f; }
  for (int c=0;c<64;c++){
    float wk = Wk[c*64+t], wv = Wvp[c*64+t];
    #pragma unroll
    for (int n=0;n<8;n++){ ka[n]+=sH[n][c]*wk; va[n]+=sH[n][c]*wv; }
  }
  for (int n=0;n<nmax;n++){ kbuf[(size_t)(n0+n)*64+t]=ka[n]; vbuf[(size_t)(n0+n)*64+t]=va[n]; }
}

__global__ __launch_bounds__(256) void k_logit(const float* __restrict__ kbuf, const float* __restrict__ qbuf,
                                               const int* __restrict__ batch,
                                               float* __restrict__ logitbuf, unsigned* __restrict__ mkey, int N){
  int wave = threadIdx.x>>6, lane = threadIdx.x&63;
  int n = blockIdx.x*4 + wave;
  if (n >= N) return;
  int g = batch[n];
  float p = kbuf[(size_t)n*64+lane]*qbuf[(size_t)g*64+lane];
  #pragma unroll
  for (int off=32; off>0; off>>=1) p += __shfl_down(p, off, 64);
  if (lane==0){
    float logit = p*0.125f;
    logitbuf[n] = logit;
    unsigned u = __float_as_uint(logit);
    unsigned key = (u & 0x80000000u) ? ~u : (u | 0x80000000u);
    atomicMax(&mkey[g], key);
  }
}

__global__ __launch_bounds__(256) void k_soft(const float* __restrict__ vbuf, const float* __restrict__ logitbuf,
                                              const int* __restrict__ batch, const unsigned* __restrict__ mkey,
                                              float* __restrict__ den, float* __restrict__ cbuf, int N){
  int wave = threadIdx.x>>6, lane = threadIdx.x&63;
  int n = blockIdx.x*4 + wave;
  if (n >= N) return;
  int g = batch[n];
  unsigned key = mkey[g];
  unsigned u = (key & 0x80000000u) ? (key ^ 0x80000000u) : ~key;
  float m = __uint_as_float(u);
  float ex = __expf(logitbuf[n] - m);
  if (lane==0) atomicAdd(&den[g], ex);
  atomicAdd(&cbuf[(size_t)g*64+lane], ex*vbuf[(size_t)n*64+lane]);
}

__global__ __launch_bounds__(192) void k_final(const float* __restrict__ hs, const float* __restrict__ hv,
                                               const float* __restrict__ ht, const int* __restrict__ absorber,
                                               const float* __restrict__ den, const float* __restrict__ cbuf,
                                               const float* __restrict__ Wr1, const float* __restrict__ br1,
                                               const float* __restrict__ Wr2, const float* __restrict__ br2,
                                               float* __restrict__ out, int G){
  __shared__ float zr[176];
  __shared__ float h1[128];
  int g = blockIdx.x, t = threadIdx.x;
  int a = absorber[g];
  if (t < 64) zr[t] = hs[(size_t)a*64+t];
  else if (t < 128){
    int f = t-64;
    zr[t] = cbuf[(size_t)g*64+f] / fmaxf(den[g], 1e-9f);
  } else if (t < 160){
    int j = t-128; float s = 0.f;
    #pragma unroll
    for (int dd=0;dd<3;dd++){ float v = hv[(size_t)a*96+j*3+dd]; s += v*v; }
    zr[t] = s;
  } else if (t < 176){
    int j = t-160; float s = 0.f;
    #pragma unroll
    for (int dd=0;dd<5;dd++){ float v = ht[(size_t)a*80+j*5+dd]; s += v*v; }
    zr[t] = s;
  }
  __syncthreads();
  if (t < 128){
    float acc = br1[t];
    for (int i=0;i<176;i++) acc += zr[i]*Wr1[i*128+t];
    h1[t] = silu_f(acc);
  }
  __syncthreads();
  if (t < 128){
    float acc = br2[t];
    for (int j=0;j<128;j++) acc += h1[j]*Wr2[j*128+t];
    out[(size_t)g*128+t] = acc;
  }
}

extern "C" void kernel_launch(void* const* d_in, const int* in_sizes, int n_in,
                              void* d_out, int out_size, void* d_ws, size_t ws_size,
                              hipStream_t stream){
  const int*   z        = (const int*)  d_in[0];
  const float* pos      = (const float*)d_in[1];
  const int*   ei       = (const int*)  d_in[2];
  const int*   batch    = (const int*)  d_in[3];
  const int*   absorber = (const int*)  d_in[4];
  const float* embed    = (const float*)d_in[5];
  const float* rW1      = (const float*)d_in[6];
  const float* rb1      = (const float*)d_in[7];
  const float* rW2      = (const float*)d_in[8];
  const float* Ws       = (const float*)d_in[9];
  const float* Wss      = (const float*)d_in[10];
  const float* Wv       = (const float*)d_in[11];
  const float* Wvv      = (const float*)d_in[12];
  const float* Wt       = (const float*)d_in[13];
  const float* Wtt      = (const float*)d_in[14];
  const float* Wq       = (const float*)d_in[15];
  const float* Wk       = (const float*)d_in[16];
  const float* Wvp      = (const float*)d_in[17];
  const float* Wr1      = (const float*)d_in[18];
  const float* br1      = (const float*)d_in[19];
  const float* Wr2      = (const float*)d_in[20];
  const float* br2      = (const float*)d_in[21];

  int N = in_sizes[0];
  int E = in_sizes[2]/2;
  int G = in_sizes[4];
  const int* srcArr = ei;
  const int* dstArr = ei + E;

  float* p = (float*)d_ws;
  float* hs    = p; p += (size_t)N*64;
  float* hv    = p; p += (size_t)N*96;
  float* ht    = p; p += (size_t)N*80;
  float* a0    = p; p += (size_t)N*112;
  float* a1    = p; p += (size_t)N*384;
  float* a2    = p; p += (size_t)N*400;
  float* rbbuf = p; p += (size_t)E*10;
  float* ybuf  = p; p += (size_t)E*9;
  float* qbuf  = p; p += (size_t)G*64;
  float* kbuf  = p; p += (size_t)N*64;
  float* vbuf  = p; p += (size_t)N*64;
  float* logitbuf = p; p += N;
  unsigned* mkey = (unsigned*)p; p += G;
  float* den   = p; p += G;
  float* cbuf  = p; p += (size_t)G*64;

  int initTot = N*96;
  k_init<<<(initTot+255)/256, 256, 0, stream>>>(z, embed, hs, hv, ht, mkey, den, cbuf, N, G);
  k_efeat<<<(E+255)/256, 256, 0, stream>>>(pos, srcArr, dstArr, rbbuf, ybuf, E);

  for (int l=0; l<NLAYERS; l++){
    hipMemsetAsync(a0, 0, (size_t)N*(112+384+400)*sizeof(float), stream);
    k_edge<<<(E+TILE_E-1)/TILE_E, 320, 0, stream>>>(hs, hv, ht, srcArr, dstArr, rbbuf, ybuf,
                                                    rW1, rb1, rW2, a0, a1, a2, E, l);
    k_node<<<(N+TILE_N-1)/TILE_N, 256, 0, stream>>>(hs, hv, ht, a0, a1, a2,
                                                    Ws, Wss, Wv, Wvv, Wt, Wtt, N, l);
  }

  k_q<<<G, 64, 0, stream>>>(hs, absorber, Wq, qbuf, G);
  k_kv<<<(N+7)/8, 64, 0, stream>>>(hs, Wk, Wvp, kbuf, vbuf, N);
  k_logit<<<(N+3)/4, 256, 0, stream>>>(kbuf, qbuf, batch, logitbuf, mkey, N);
  k_soft<<<(N+3)/4, 256, 0, stream>>>(vbuf, logitbuf, batch, mkey, den, cbuf, N);
  k_final<<<G, 192, 0, stream>>>(hs, hv, ht, absorber, den, cbuf, Wr1, br1, Wr2, br2, (float*)d_out, G);
}